// Round 9
// baseline (194.496 us; speedup 1.0000x reference)
//
#include <hip/hip_runtime.h>
#include <math.h>

typedef __attribute__((ext_vector_type(8))) short bf16x8;   // 8 bf16 = 4 VGPRs
typedef __attribute__((ext_vector_type(4))) float f32x4;    // MFMA acc

#define NEXP 8
#define BATCH 2048

__device__ __forceinline__ unsigned short f2bf(float f) {
    union { float f; unsigned u; } v; v.f = f;
    unsigned r = v.u + 0x7FFFu + ((v.u >> 16) & 1u);   // RTNE
    return (unsigned short)(r >> 16);
}

__device__ __forceinline__ float elu_fast(float v) {
    return v > 0.f ? v : (exp2f(v * 1.4426950408889634f) - 1.0f);
}

// async global->LDS, 16B per lane; LDS dest = wave-uniform base + lane*16.
__device__ __forceinline__ void gl_lds(const char* g, char* l) {
    __builtin_amdgcn_global_load_lds(
        (const __attribute__((address_space(1))) void*)g,
        (__attribute__((address_space(3))) void*)l, 16, 0, 0);
}

// ---------------------------------------------------------------------------
// Fragment-packing converter (unchanged from R0/R3).
// ---------------------------------------------------------------------------
__global__ __launch_bounds__(256) void pack_all(
    const float* __restrict__ W0, const float* __restrict__ W1,
    const float* __restrict__ W2, const float* __restrict__ x,
    unsigned short* __restrict__ W0p, unsigned short* __restrict__ W1p,
    unsigned short* __restrict__ W2p, unsigned short* __restrict__ x0p)
{
    __shared__ float T[128 * 36];
    const int bid = blockIdx.x, t = threadIdx.x;

    if (bid < 10240) {
        const float* W; unsigned short* out; int KB, Din, Dout, U, lin;
        if (bid < 2048)      { W = W0; out = W0p; KB = 16; Din = 512;  Dout = 1024; U = 4; lin = bid; }
        else if (bid < 6144) { W = W1; out = W1p; KB = 32; Din = 1024; Dout = 1024; U = 4; lin = bid - 2048; }
        else                 { W = W2; out = W2p; KB = 32; Din = 1024; Dout = 512;  U = 2; lin = bid - 6144; }
        const int e  = lin & 7;
        const int r  = lin >> 3;
        const int kb = r % KB;
        const int nb = r / KB;
        const int N0 = nb * 16 * U;
        const int K0 = kb * 32;
        for (int it = 0; it < U / 2; ++it) {
            const int idx = t + 256 * it;
            const int nl = idx >> 3, k4 = (idx & 7) * 4;
            float4 v = *(const float4*)(W + ((size_t)e * Dout + N0 + nl) * Din + K0 + k4);
            *(float4*)(T + nl * 36 + k4) = v;
        }
        __syncthreads();
        if (t < 64 * U) {
            const int u = t >> 6, l = t & 63;
            const float* p = T + (u * 16 + (l & 15)) * 36 + (l >> 4) * 8;
            bf16x8 h;
            #pragma unroll
            for (int j = 0; j < 8; ++j) h[j] = (short)f2bf(p[j]);
            *(bf16x8*)(out + (size_t)lin * (U * 512) + t * 8) = h;
        }
    } else {
        const int lin = bid - 10240;
        const int kb = lin & 15, mb = lin >> 4;
        for (int it = 0; it < 4; ++it) {
            const int idx = t + 256 * it;
            const int ml = idx >> 3, k4 = (idx & 7) * 4;
            float4 v = *(const float4*)(x + (size_t)(mb * 128 + ml) * 512 + kb * 32 + k4);
            *(float4*)(T + ml * 36 + k4) = v;
        }
        __syncthreads();
        #pragma unroll
        for (int it = 0; it < 2; ++it) {
            const int s = t + 256 * it;
            const int g = s >> 6, l = s & 63;
            const float* p = T + (g * 16 + (l & 15)) * 36 + (l >> 4) * 8;
            bf16x8 h;
            #pragma unroll
            for (int j = 0; j < 8; ++j) h[j] = (short)f2bf(p[j]);
            *(bf16x8*)(x0p + (size_t)lin * 4096 + s * 8) = h;
        }
    }
}

// ---------------------------------------------------------------------------
// LDS-staged 8-wave 128m x 64n block (l0/l1), DEPTH-3 pipeline with counted
// vmcnt (T4): 3 x 40 KB staging buffers; per kk issue STAGE(kk+2), then
// s_waitcnt vmcnt(10) (drains only stage kk, issued 2 iterations ago ->
// wait ~free; stages kk+1/kk+2 stay in flight ACROSS the barrier), raw
// s_barrier + sched_barrier(0) (pins ds_reads below barrier, rule #18),
// COMPUTE, raw s_barrier (frees slot (kk)%3; WAR-safe: slot staged at kk+2
// was freed by iteration kk-1's end barrier). Tail: vmcnt(5), vmcnt(0).
// Frag table / compute / epilogue identical to R8.
// ---------------------------------------------------------------------------
template<int UP>
__device__ __forceinline__ void moe_stage(
    char* smem, int bx, int by,
    const unsigned short* __restrict__ Xp,
    const unsigned short* __restrict__ Wp,
    const float* __restrict__ Bias,
    const float* __restrict__ WBl,
    unsigned short* __restrict__ Yout,
    int KB, int Dout, int KBn)
{
    constexpr int PSTR = 68;                 // epilogue f32 row stride
    constexpr unsigned BUFB = 40 * 1024;     // staging buffer bytes

    const int tid  = threadIdx.x;
    const int wv   = tid >> 6;               // 0..7
    const int mh   = wv >> 2;                // m-half
    const int ew   = wv & 3;                 // expert pair
    const int l    = tid & 63;
    const int lh   = l >> 4;
    const int ll   = l & 15;
    const int e0   = 2 * ew;
    const int m0   = by * 128 + mh * 64;
    const int n0   = bx * 64;
    const int mb   = by;

    f32x4 acc0[4][4], acc1[4][4];
    #pragma unroll
    for (int t = 0; t < 4; ++t)
        #pragma unroll
        for (int u = 0; u < 4; ++u)
            #pragma unroll
            for (int i = 0; i < 4; ++i) { acc0[t][u][i] = 0.f; acc1[t][u][i] = 0.f; }

    // ---- staging slot table: wave wv owns fids [wv*5, wv*5+5) of 40 ----
    const char* xc = (const char*)Xp;
    const char* wc = (const char*)Wp;
    const int fidbase = wv * 5;
    const char* gp[5]; unsigned kst[5];
    #pragma unroll
    for (int s = 0; s < 5; ++s) {
        const int fid = fidbase + s;
        if (fid < 8) {
            gp[s]  = xc + (unsigned)(mb * KB) * 8192u + (unsigned)fid * 1024u + l * 16u;
            kst[s] = 8192u;
        } else {
            const int idx = fid - 8;
            const int e   = 2 * (idx >> 3) + ((idx >> 2) & 1);
            const int u   = idx & 3;
            const int fn  = bx * 4 + u;
            const int nb  = fn / UP;
            const int uu  = fn % UP;
            gp[s]  = wc + (unsigned)((nb * KB * 8 + e) * UP + uu) * 1024u + l * 16u;
            kst[s] = UP * 8192u;
        }
    }

    auto STAGE = [&](int b, int kk) {
        char* lb = smem + (unsigned)b * BUFB + (unsigned)fidbase * 1024u;
        #pragma unroll
        for (int s = 0; s < 5; ++s)
            gl_lds(gp[s] + (unsigned)kk * kst[s], lb + s * 1024);
    };

    auto COMPUTE = [&](int b) {
        const char* sb = smem + (unsigned)b * BUFB;
        bf16x8 aR[4], b0R[4], b1R[4];
        #pragma unroll
        for (int t = 0; t < 4; ++t)
            aR[t] = *(const bf16x8*)(sb + (mh * 4 + t) * 1024 + l * 16);
        #pragma unroll
        for (int u = 0; u < 4; ++u) {
            b0R[u] = *(const bf16x8*)(sb + (8 + ew * 8 + u) * 1024 + l * 16);
            b1R[u] = *(const bf16x8*)(sb + (8 + ew * 8 + 4 + u) * 1024 + l * 16);
        }
        __builtin_amdgcn_s_setprio(1);
        #pragma unroll
        for (int u = 0; u < 4; ++u)
            #pragma unroll
            for (int t = 0; t < 4; ++t) {
                acc0[t][u] = __builtin_amdgcn_mfma_f32_16x16x32_bf16(aR[t], b0R[u], acc0[t][u], 0, 0, 0);
                acc1[t][u] = __builtin_amdgcn_mfma_f32_16x16x32_bf16(aR[t], b1R[u], acc1[t][u], 0, 0, 0);
            }
        __builtin_amdgcn_s_setprio(0);
    };

    // ---- depth-3 counted-vmcnt k-loop ----
    STAGE(0, 0);
    STAGE(1, 1);
    for (int kk = 0; kk < KB; ++kk) {
        if (kk + 2 < KB) {
            STAGE((kk + 2) % 3, kk + 2);
            __builtin_amdgcn_sched_barrier(0);           // pin stage before wait
            asm volatile("s_waitcnt vmcnt(10)" ::: "memory");  // stage kk done
        } else if (kk + 1 < KB) {
            asm volatile("s_waitcnt vmcnt(5)" ::: "memory");
        } else {
            asm volatile("s_waitcnt vmcnt(0)" ::: "memory");
        }
        __builtin_amdgcn_s_barrier();                    // buffer kk visible
        __builtin_amdgcn_sched_barrier(0);               // no ds_read hoisting
        COMPUTE(kk % 3);
        __builtin_amdgcn_s_barrier();                    // slot kk free
    }

    // ---- epilogue (R8 two-pass), smem reused as f32 buffers ----
    float* epi = (float*)smem;
    float bi0[4], bi1[4];
    #pragma unroll
    for (int u = 0; u < 4; ++u) {
        const int n = n0 + u * 16 + ll;
        bi0[u] = Bias[(size_t)e0 * Dout + n];
        bi1[u] = Bias[(size_t)(e0 + 1) * Dout + n];
    }
    float2 wbp[4][4];
    #pragma unroll
    for (int t = 0; t < 4; ++t)
        #pragma unroll
        for (int r = 0; r < 4; ++r) {
            const int lm = 16 * t + 4 * lh + r;
            wbp[t][r] = ((const float2*)(WBl + (size_t)(m0 + lm) * NEXP))[ew];
        }

    float* pb = epi + ew * (64 * PSTR);
    #pragma unroll
    for (int h = 0; h < 2; ++h) {
        if (mh == h) {
            #pragma unroll
            for (int t = 0; t < 4; ++t)
                #pragma unroll
                for (int r = 0; r < 4; ++r) {
                    const int lm = 16 * t + 4 * lh + r;
                    #pragma unroll
                    for (int u = 0; u < 4; ++u)
                        pb[lm * PSTR + u * 16 + ll] =
                            wbp[t][r].x * (acc0[t][u][r] + bi0[u]) + wbp[t][r].y * (acc1[t][u][r] + bi1[u]);
                }
        }
        __syncthreads();
        {
            const int kbh = wv >> 2;
            const int g   = wv & 3;
            const int rb  = (g * 16 + ll) * PSTR + kbh * 32 + lh * 8;
            bf16x8 hx;
            #pragma unroll
            for (int j = 0; j < 8; ++j) {
                float v = epi[0 * 64 * PSTR + rb + j]
                        + epi[1 * 64 * PSTR + rb + j]
                        + epi[2 * 64 * PSTR + rb + j]
                        + epi[3 * 64 * PSTR + rb + j];
                v = elu_fast(v);
                hx[j] = (short)f2bf(v);
            }
            unsigned short* dst = Yout +
                ((size_t)(mb * KBn + bx * 2 + kbh) * 8 + h * 4 + g) * 512 + l * 8;
            *(bf16x8*)dst = hx;
        }
        if (h == 0) __syncthreads();
    }
}

// ---------------------------------------------------------------------------
// 4-wave 64m x (NU*16)n body (l2) — unchanged from R6.
// ---------------------------------------------------------------------------
template<int UP, int NU>
__device__ __forceinline__ void moe_body(
    float* lds_f, int bx, int by,
    const unsigned short* __restrict__ Xp,
    const unsigned short* __restrict__ Wp,
    const float* __restrict__ Bias,
    const float* __restrict__ WBl,
    void* __restrict__ Yout,
    int KB, int Dout, int KBn, int act, int packed_out)
{
    constexpr int PSTR = NU * 16 + 4;

    const int tid  = threadIdx.x;
    const int ew   = tid >> 6;
    const int l    = tid & 63;
    const int lh   = l >> 4;
    const int ll   = l & 15;
    const int e0   = 2 * ew;
    const int m0   = by * 64;
    const int n0   = bx * (NU * 16);
    const int mb   = by >> 1;
    const int half = by & 1;

    f32x4 acc0[4][NU], acc1[4][NU];
    #pragma unroll
    for (int t = 0; t < 4; ++t)
        #pragma unroll
        for (int u = 0; u < NU; ++u)
            #pragma unroll
            for (int i = 0; i < 4; ++i) { acc0[t][u][i] = 0.f; acc1[t][u][i] = 0.f; }

    unsigned aoff[4];
    #pragma unroll
    for (int t = 0; t < 4; ++t)
        aoff[t] = (unsigned)(mb * KB) * 8192u + (unsigned)(half * 4 + t) * 1024u + l * 16u;
    unsigned boff0[NU], boff1[NU];
    #pragma unroll
    for (int u = 0; u < NU; ++u) {
        const int fn = bx * NU + u;
        const int nb = fn / UP;
        const int uu = fn % UP;
        boff0[u] = (((unsigned)(nb * KB) * 8 + e0) * UP + uu) * 1024u + l * 16u;
        boff1[u] = boff0[u] + UP * 1024u;
    }
    const unsigned astr = 8192u;
    const unsigned bstr = UP * 8192u;
    const char* xc = (const char*)Xp;
    const char* wc = (const char*)Wp;

    bf16x8 aR[2][4], b0R[2][NU], b1R[2][NU];

    auto LOAD = [&](int s, int kk) {
        const unsigned ab = (unsigned)kk * astr;
        const unsigned bb = (unsigned)kk * bstr;
        #pragma unroll
        for (int t = 0; t < 4; ++t)
            aR[s][t] = *(const bf16x8*)(xc + aoff[t] + ab);
        #pragma unroll
        for (int u = 0; u < NU; ++u) {
            b0R[s][u] = *(const bf16x8*)(wc + boff0[u] + bb);
            b1R[s][u] = *(const bf16x8*)(wc + boff1[u] + bb);
        }
    };
    auto MF = [&](int s) {
        __builtin_amdgcn_s_setprio(1);
        #pragma unroll
        for (int u = 0; u < NU; ++u)
            #pragma unroll
            for (int t = 0; t < 4; ++t) {
                acc0[t][u] = __builtin_amdgcn_mfma_f32_16x16x32_bf16(aR[s][t], b0R[s][u], acc0[t][u], 0, 0, 0);
                acc1[t][u] = __builtin_amdgcn_mfma_f32_16x16x32_bf16(aR[s][t], b1R[s][u], acc1[t][u], 0, 0, 0);
            }
        __builtin_amdgcn_s_setprio(0);
    };

    LOAD(0, 0);
    for (int kk = 0; kk < KB; kk += 2) {
        if (kk + 1 < KB) LOAD(1, kk + 1);
        MF(0);
        if (kk + 2 < KB) LOAD(0, kk + 2);
        MF(1);
    }

    float bi0[NU], bi1[NU];
    #pragma unroll
    for (int u = 0; u < NU; ++u) {
        const int n = n0 + u * 16 + ll;
        bi0[u] = Bias[(size_t)e0 * Dout + n];
        bi1[u] = Bias[(size_t)(e0 + 1) * Dout + n];
    }
    float2 wbp[4][4];
    #pragma unroll
    for (int t = 0; t < 4; ++t)
        #pragma unroll
        for (int r = 0; r < 4; ++r) {
            const int lm = 16 * t + 4 * lh + r;
            wbp[t][r] = ((const float2*)(WBl + (size_t)(m0 + lm) * NEXP))[ew];
        }

    float* pb = lds_f + ew * (64 * PSTR);
    #pragma unroll
    for (int t = 0; t < 4; ++t)
        #pragma unroll
        for (int r = 0; r < 4; ++r) {
            const int lm = 16 * t + 4 * lh + r;
            #pragma unroll
            for (int u = 0; u < NU; ++u)
                pb[lm * PSTR + u * 16 + ll] =
                    wbp[t][r].x * (acc0[t][u][r] + bi0[u]) + wbp[t][r].y * (acc1[t][u][r] + bi1[u]);
        }
    __syncthreads();

    if (packed_out) {
        if constexpr (NU == 4) {
            #pragma unroll
            for (int it = 0; it < 2; ++it) {
                const int kbh = it;
                const int g   = tid >> 6;
                const int le  = tid & 63;
                const int lhh = le >> 4, lle = le & 15;
                const int rb  = (g * 16 + lle) * PSTR + kbh * 32 + lhh * 8;
                bf16x8 h;
                #pragma unroll
                for (int j = 0; j < 8; ++j) {
                    float v = lds_f[0 * 64 * PSTR + rb + j]
                            + lds_f[1 * 64 * PSTR + rb + j]
                            + lds_f[2 * 64 * PSTR + rb + j]
                            + lds_f[3 * 64 * PSTR + rb + j];
                    if (act) v = elu_fast(v);
                    h[j] = (short)f2bf(v);
                }
                unsigned short* dst = (unsigned short*)Yout +
                    ((size_t)(mb * KBn + bx * 2 + kbh) * 8 + half * 4 + g) * 512 + le * 8;
                *(bf16x8*)dst = h;
            }
        }
    } else {
        constexpr int F4R = NU * 4;
        #pragma unroll
        for (int it = 0; it < NU; ++it) {
            const int idx = tid + 256 * it;
            const int row = idx / F4R;
            const int c4  = (idx % F4R) * 4;
            const int rb  = row * PSTR + c4;
            float4 s  = *(const float4*)(lds_f + 0 * 64 * PSTR + rb);
            float4 q1 = *(const float4*)(lds_f + 1 * 64 * PSTR + rb);
            float4 q2 = *(const float4*)(lds_f + 2 * 64 * PSTR + rb);
            float4 q3 = *(const float4*)(lds_f + 3 * 64 * PSTR + rb);
            s.x += q1.x + q2.x + q3.x;
            s.y += q1.y + q2.y + q3.y;
            s.z += q1.z + q2.z + q3.z;
            s.w += q1.w + q2.w + q3.w;
            if (act) {
                s.x = elu_fast(s.x);
                s.y = elu_fast(s.y);
                s.z = elu_fast(s.z);
                s.w = elu_fast(s.w);
            }
            *(float4*)((float*)Yout + (size_t)(m0 + row) * Dout + n0 + c4) = s;
        }
    }
}

// ---------------------------------------------------------------------------
// Swizzles (unchanged).
// ---------------------------------------------------------------------------
__device__ __forceinline__ void swz256(int& bx, int& by) {
    const int bid = blockIdx.x;
    const int xcd = bid & 7;
    const int loc = bid >> 3;                // 0..31
    bx = xcd * 2 + (loc & 1);                // 0..15
    by = loc >> 1;                           // 0..15
}
__device__ __forceinline__ void swz_pair(int& bx, int& by) {
    const int bid = blockIdx.x;
    const int xcd = bid & 7;
    const int loc = bid >> 3;                // 0..63
    bx = xcd * 2 + (loc & 1);                // 0..15
    by = loc >> 1;                           // 0..31
}

// Per-layer kernels.
__global__ __launch_bounds__(512, 1) void moe_l0(
    const unsigned short* __restrict__ Xp, const unsigned short* __restrict__ Wp,
    const float* __restrict__ Bias, const float* __restrict__ WBl,
    unsigned short* __restrict__ Yout, int KB, int Dout, int KBn)
{
    __shared__ __align__(16) char smem[3 * 40 * 1024];   // 120 KB
    int bx, by; swz256(bx, by);
    moe_stage<4>(smem, bx, by, Xp, Wp, Bias, WBl, Yout, KB, Dout, KBn);
}
__global__ __launch_bounds__(512, 1) void moe_l1(
    const unsigned short* __restrict__ Xp, const unsigned short* __restrict__ Wp,
    const float* __restrict__ Bias, const float* __restrict__ WBl,
    unsigned short* __restrict__ Yout, int KB, int Dout, int KBn)
{
    __shared__ __align__(16) char smem[3 * 40 * 1024];
    int bx, by; swz256(bx, by);
    moe_stage<4>(smem, bx, by, Xp, Wp, Bias, WBl, Yout, KB, Dout, KBn);
}
// l2: 64m x 32n tile (NU=2), 512 blocks, 2/CU, f32 row-major out.
__global__ __launch_bounds__(256, 2) void moe_l2(
    const unsigned short* __restrict__ Xp, const unsigned short* __restrict__ Wp,
    const float* __restrict__ Bias, const float* __restrict__ WBl,
    void* __restrict__ Yout, int KB, int Dout, int KBn, int act, int packed_out)
{
    __shared__ __align__(16) float lds_f[4 * 64 * 36];
    int bx, by; swz_pair(bx, by);
    moe_body<2, 2>(lds_f, bx, by, Xp, Wp, Bias, WBl, Yout, KB, Dout, KBn, act, packed_out);
}

// ---------------- fp32 fallback for small ws_size ----------------
#define BM 64
#define BNF 64
#define BKF 16
#define PAD 4

__global__ __launch_bounds__(256) void moe_layer_f32(
    const float* __restrict__ X, const float* __restrict__ W,
    const float* __restrict__ Bias, const float* __restrict__ WB,
    float* __restrict__ Y, int Din, int Dout, int act)
{
    __shared__ float As[BKF][BM + PAD];
    __shared__ float Bs[BKF][BNF + PAD];
    const int tid = threadIdx.x;
    const int tm = tid >> 4, tn = tid & 15;
    const int m0 = blockIdx.y * BM, n0 = blockIdx.x * BNF;
    const int lr = tid >> 2, lc = (tid & 3) << 2;
    float acc[4][4] = {};
    const float* xrow  = X  + (size_t)(m0 + lr) * Din;
    const float* wbrow = WB + (size_t)(m0 + lr) * NEXP;
    const float* wrow0 = W  + (size_t)(n0 + lr) * Din;
    for (int e = 0; e < NEXP; ++e) {
        const float wbe = wbrow[e];
        const float* wrow = wrow0 + (size_t)e * Dout * Din;
        for (int k0 = 0; k0 < Din; k0 += BKF) {
            float4 av = *(const float4*)(xrow + k0 + lc);
            float4 bv = *(const float4*)(wrow + k0 + lc);
            __syncthreads();
            As[lc+0][lr] = av.x*wbe; As[lc+1][lr] = av.y*wbe;
            As[lc+2][lr] = av.z*wbe; As[lc+3][lr] = av.w*wbe;
            Bs[lc+0][lr] = bv.x; Bs[lc+1][lr] = bv.y;
            Bs[lc+2][lr] = bv.z; Bs[lc+3][lr] = bv.w;
            __syncthreads();
            #pragma unroll
            for (int k = 0; k < BKF; ++k) {
                float4 a = *(const float4*)&As[k][tm << 2];
                float4 b = *(const float4*)&Bs[k][tn << 2];
                acc[0][0]+=a.x*b.x; acc[0][1]+=a.x*b.y; acc[0][2]+=a.x*b.z; acc[0][3]+=a.x*b.w;
                acc[1][0]+=a.y*b.x; acc[1][1]+=a.y*b.y; acc[1][2]+=a.y*b.z; acc[1][3]+=a.y*b.w;
                acc[2][0]+=a.z*b.x; acc[2][1]+=a.z*b.y; acc[2][2]+=a.z*b.z; acc[2][3]+=a.z*b.w;
                acc[3][0]+=a.w*b.x; acc[3][1]+=a.w*b.y; acc[3][2]+=a.w*b.z; acc[3][3]+=a.w*b.w;
            }
        }
    }
    #pragma unroll
    for (int im = 0; im < 4; ++im) {
        const int m = m0 + (tm << 2) + im;
        const float* wbm = WB + (size_t)m * NEXP;
        float wv[NEXP];
        #pragma unroll
        for (int e = 0; e < NEXP; ++e) wv[e] = wbm[e];
        #pragma unroll
        for (int in = 0; in < 4; ++in) {
            const int n = n0 + (tn << 2) + in;
            float bsum = 0.f;
            #pragma unroll
            for (int e = 0; e < NEXP; ++e) bsum += wv[e] * Bias[(size_t)e * Dout + n];
            float v = acc[im][in] + bsum;
            if (act) v = v > 0.f ? v : expm1f(v);
            acc[im][in] = v;
        }
        float4 o = make_float4(acc[im][0], acc[im][1], acc[im][2], acc[im][3]);
        *(float4*)(Y + (size_t)m * Dout + n0 + (tn << 2)) = o;
    }
}

extern "C" void kernel_launch(void* const* d_in, const int* in_sizes, int n_in,
                              void* d_out, int out_size, void* d_ws, size_t ws_size,
                              hipStream_t stream)
{
    (void)in_sizes; (void)n_in; (void)out_size;
    const float* wb = (const float*)d_in[0];
    const float* x  = (const float*)d_in[1];
    const float* W0 = (const float*)d_in[2];
    const float* B0 = (const float*)d_in[3];
    const float* W1 = (const float*)d_in[4];
    const float* B1 = (const float*)d_in[5];
    const float* W2 = (const float*)d_in[6];
    const float* B2 = (const float*)d_in[7];
    float* out = (float*)d_out;

    const size_t NW0 = (size_t)8*1024*512, NW1 = (size_t)8*1024*1024, NW2 = (size_t)8*512*1024;
    const size_t NX0 = (size_t)BATCH*512, NX1 = (size_t)BATCH*1024;
    const size_t need = (NW0 + NW1 + NW2 + NX0 + 2 * NX1) * 2;   // ~44 MB bf16

    if (ws_size >= need) {
        unsigned short* W0p = (unsigned short*)d_ws;
        unsigned short* W1p = W0p + NW0;
        unsigned short* W2p = W1p + NW1;
        unsigned short* x0p = W2p + NW2;
        unsigned short* x1p = x0p + NX0;
        unsigned short* x2p = x1p + NX1;
        pack_all<<<10496, 256, 0, stream>>>(W0, W1, W2, x, W0p, W1p, W2p, x0p);
        moe_l0<<<256, 512, 0, stream>>>(x0p, W0p, B0, wb, x1p, 16, 1024, 32);
        moe_l1<<<256, 512, 0, stream>>>(x1p, W1p, B1, wb, x2p, 32, 1024, 32);
        moe_l2<<<512, 256, 0, stream>>>(x2p, W2p, B2, wb, out, 32, 512,  0, 0, 0);
    } else {
        float* x1 = (float*)d_ws;
        float* x2 = x1 + (size_t)BATCH * 1024;
        moe_layer_f32<<<dim3(1024/BNF, BATCH/BM), 256, 0, stream>>>(x,  W0, B0, wb, x1, 512,  1024, 1);
        moe_layer_f32<<<dim3(1024/BNF, BATCH/BM), 256, 0, stream>>>(x1, W1, B1, wb, x2, 1024, 1024, 1);
        moe_layer_f32<<<dim3(512/BNF,  BATCH/BM), 256, 0, stream>>>(x2, W2, B2, wb, out, 1024, 512,  0);
    }
}

// Round 10
// 186.209 us; speedup vs baseline: 1.0445x; 1.0445x over previous
//
#include <hip/hip_runtime.h>
#include <math.h>

typedef __attribute__((ext_vector_type(8))) short bf16x8;   // 8 bf16 = 4 VGPRs
typedef __attribute__((ext_vector_type(4))) float f32x4;    // MFMA acc

#define NEXP 8
#define BATCH 2048

__device__ __forceinline__ unsigned short f2bf(float f) {
    union { float f; unsigned u; } v; v.f = f;
    unsigned r = v.u + 0x7FFFu + ((v.u >> 16) & 1u);   // RTNE
    return (unsigned short)(r >> 16);
}

__device__ __forceinline__ float elu_fast(float v) {
    return v > 0.f ? v : (exp2f(v * 1.4426950408889634f) - 1.0f);
}

// async global->LDS, 16B per lane; LDS dest = wave-uniform base + lane*16.
__device__ __forceinline__ void gl_lds(const char* g, char* l) {
    __builtin_amdgcn_global_load_lds(
        (const __attribute__((address_space(1))) void*)g,
        (__attribute__((address_space(3))) void*)l, 16, 0, 0);
}

// ---------------------------------------------------------------------------
// Fragment-packing converter (unchanged from R0/R3).
// ---------------------------------------------------------------------------
__global__ __launch_bounds__(256) void pack_all(
    const float* __restrict__ W0, const float* __restrict__ W1,
    const float* __restrict__ W2, const float* __restrict__ x,
    unsigned short* __restrict__ W0p, unsigned short* __restrict__ W1p,
    unsigned short* __restrict__ W2p, unsigned short* __restrict__ x0p)
{
    __shared__ float T[128 * 36];
    const int bid = blockIdx.x, t = threadIdx.x;

    if (bid < 10240) {
        const float* W; unsigned short* out; int KB, Din, Dout, U, lin;
        if (bid < 2048)      { W = W0; out = W0p; KB = 16; Din = 512;  Dout = 1024; U = 4; lin = bid; }
        else if (bid < 6144) { W = W1; out = W1p; KB = 32; Din = 1024; Dout = 1024; U = 4; lin = bid - 2048; }
        else                 { W = W2; out = W2p; KB = 32; Din = 1024; Dout = 512;  U = 2; lin = bid - 6144; }
        const int e  = lin & 7;
        const int r  = lin >> 3;
        const int kb = r % KB;
        const int nb = r / KB;
        const int N0 = nb * 16 * U;
        const int K0 = kb * 32;
        for (int it = 0; it < U / 2; ++it) {
            const int idx = t + 256 * it;
            const int nl = idx >> 3, k4 = (idx & 7) * 4;
            float4 v = *(const float4*)(W + ((size_t)e * Dout + N0 + nl) * Din + K0 + k4);
            *(float4*)(T + nl * 36 + k4) = v;
        }
        __syncthreads();
        if (t < 64 * U) {
            const int u = t >> 6, l = t & 63;
            const float* p = T + (u * 16 + (l & 15)) * 36 + (l >> 4) * 8;
            bf16x8 h;
            #pragma unroll
            for (int j = 0; j < 8; ++j) h[j] = (short)f2bf(p[j]);
            *(bf16x8*)(out + (size_t)lin * (U * 512) + t * 8) = h;
        }
    } else {
        const int lin = bid - 10240;
        const int kb = lin & 15, mb = lin >> 4;
        for (int it = 0; it < 4; ++it) {
            const int idx = t + 256 * it;
            const int ml = idx >> 3, k4 = (idx & 7) * 4;
            float4 v = *(const float4*)(x + (size_t)(mb * 128 + ml) * 512 + kb * 32 + k4);
            *(float4*)(T + ml * 36 + k4) = v;
        }
        __syncthreads();
        #pragma unroll
        for (int it = 0; it < 2; ++it) {
            const int s = t + 256 * it;
            const int g = s >> 6, l = s & 63;
            const float* p = T + (g * 16 + (l & 15)) * 36 + (l >> 4) * 8;
            bf16x8 h;
            #pragma unroll
            for (int j = 0; j < 8; ++j) h[j] = (short)f2bf(p[j]);
            *(bf16x8*)(x0p + (size_t)lin * 4096 + s * 8) = h;
        }
    }
}

// ---------------------------------------------------------------------------
// LDS-staged 8-wave 128m x 64n block (l0/l1) — EXACT R8 structure (186.9 us
// best): per kk stage the block's 40 distinct 1-KB frags via global_load_lds
// width-16 (5/wave), double-buffered, 1 barrier per kk; ds_read_b128 frags;
// setprio around MFMA cluster. LDS 2 x 40 KB unions 69.6 KB epilogue.
// ---------------------------------------------------------------------------
template<int UP>
__device__ __forceinline__ void moe_stage(
    char* smem, int bx, int by,
    const unsigned short* __restrict__ Xp,
    const unsigned short* __restrict__ Wp,
    const float* __restrict__ Bias,
    const float* __restrict__ WBl,
    unsigned short* __restrict__ Yout,
    int KB, int Dout, int KBn)
{
    constexpr int PSTR = 68;                 // epilogue f32 row stride
    constexpr unsigned BUFB = 40 * 1024;     // staging buffer bytes

    const int tid  = threadIdx.x;
    const int wv   = tid >> 6;               // 0..7
    const int mh   = wv >> 2;                // m-half
    const int ew   = wv & 3;                 // expert pair
    const int l    = tid & 63;
    const int lh   = l >> 4;
    const int ll   = l & 15;
    const int e0   = 2 * ew;
    const int m0   = by * 128 + mh * 64;
    const int n0   = bx * 64;
    const int mb   = by;

    f32x4 acc0[4][4], acc1[4][4];
    #pragma unroll
    for (int t = 0; t < 4; ++t)
        #pragma unroll
        for (int u = 0; u < 4; ++u)
            #pragma unroll
            for (int i = 0; i < 4; ++i) { acc0[t][u][i] = 0.f; acc1[t][u][i] = 0.f; }

    // ---- staging slot table: wave wv owns fids [wv*5, wv*5+5) of 40 ----
    const char* xc = (const char*)Xp;
    const char* wc = (const char*)Wp;
    const int fidbase = wv * 5;
    const char* gp[5]; unsigned kst[5];
    #pragma unroll
    for (int s = 0; s < 5; ++s) {
        const int fid = fidbase + s;
        if (fid < 8) {
            gp[s]  = xc + (unsigned)(mb * KB) * 8192u + (unsigned)fid * 1024u + l * 16u;
            kst[s] = 8192u;
        } else {
            const int idx = fid - 8;
            const int e   = 2 * (idx >> 3) + ((idx >> 2) & 1);
            const int u   = idx & 3;
            const int fn  = bx * 4 + u;
            const int nb  = fn / UP;
            const int uu  = fn % UP;
            gp[s]  = wc + (unsigned)((nb * KB * 8 + e) * UP + uu) * 1024u + l * 16u;
            kst[s] = UP * 8192u;
        }
    }

    auto STAGE = [&](int b, int kk) {
        char* lb = smem + (unsigned)b * BUFB + (unsigned)fidbase * 1024u;
        #pragma unroll
        for (int s = 0; s < 5; ++s)
            gl_lds(gp[s] + (unsigned)kk * kst[s], lb + s * 1024);
    };

    auto COMPUTE = [&](int b) {
        const char* sb = smem + (unsigned)b * BUFB;
        bf16x8 aR[4], b0R[4], b1R[4];
        #pragma unroll
        for (int t = 0; t < 4; ++t)
            aR[t] = *(const bf16x8*)(sb + (mh * 4 + t) * 1024 + l * 16);
        #pragma unroll
        for (int u = 0; u < 4; ++u) {
            b0R[u] = *(const bf16x8*)(sb + (8 + ew * 8 + u) * 1024 + l * 16);
            b1R[u] = *(const bf16x8*)(sb + (8 + ew * 8 + 4 + u) * 1024 + l * 16);
        }
        __builtin_amdgcn_s_setprio(1);
        #pragma unroll
        for (int u = 0; u < 4; ++u)
            #pragma unroll
            for (int t = 0; t < 4; ++t) {
                acc0[t][u] = __builtin_amdgcn_mfma_f32_16x16x32_bf16(aR[t], b0R[u], acc0[t][u], 0, 0, 0);
                acc1[t][u] = __builtin_amdgcn_mfma_f32_16x16x32_bf16(aR[t], b1R[u], acc1[t][u], 0, 0, 0);
            }
        __builtin_amdgcn_s_setprio(0);
    };

    // ---- m97 2-barrier double-buffered k-loop (R8) ----
    STAGE(0, 0);
    __syncthreads();
    for (int kk = 0; kk < KB; ++kk) {
        if (kk + 1 < KB) STAGE((kk + 1) & 1, kk + 1);
        COMPUTE(kk & 1);
        __syncthreads();
    }

    // ---- epilogue (two-pass), smem reused as f32 buffers ----
    float* epi = (float*)smem;
    float bi0[4], bi1[4];
    #pragma unroll
    for (int u = 0; u < 4; ++u) {
        const int n = n0 + u * 16 + ll;
        bi0[u] = Bias[(size_t)e0 * Dout + n];
        bi1[u] = Bias[(size_t)(e0 + 1) * Dout + n];
    }
    float2 wbp[4][4];
    #pragma unroll
    for (int t = 0; t < 4; ++t)
        #pragma unroll
        for (int r = 0; r < 4; ++r) {
            const int lm = 16 * t + 4 * lh + r;
            wbp[t][r] = ((const float2*)(WBl + (size_t)(m0 + lm) * NEXP))[ew];
        }

    float* pb = epi + ew * (64 * PSTR);
    #pragma unroll
    for (int h = 0; h < 2; ++h) {
        if (mh == h) {
            #pragma unroll
            for (int t = 0; t < 4; ++t)
                #pragma unroll
                for (int r = 0; r < 4; ++r) {
                    const int lm = 16 * t + 4 * lh + r;
                    #pragma unroll
                    for (int u = 0; u < 4; ++u)
                        pb[lm * PSTR + u * 16 + ll] =
                            wbp[t][r].x * (acc0[t][u][r] + bi0[u]) + wbp[t][r].y * (acc1[t][u][r] + bi1[u]);
                }
        }
        __syncthreads();
        {
            const int kbh = wv >> 2;
            const int g   = wv & 3;
            const int rb  = (g * 16 + ll) * PSTR + kbh * 32 + lh * 8;
            bf16x8 hx;
            #pragma unroll
            for (int j = 0; j < 8; ++j) {
                float v = epi[0 * 64 * PSTR + rb + j]
                        + epi[1 * 64 * PSTR + rb + j]
                        + epi[2 * 64 * PSTR + rb + j]
                        + epi[3 * 64 * PSTR + rb + j];
                v = elu_fast(v);
                hx[j] = (short)f2bf(v);
            }
            unsigned short* dst = Yout +
                ((size_t)(mb * KBn + bx * 2 + kbh) * 8 + h * 4 + g) * 512 + l * 8;
            *(bf16x8*)dst = hx;
        }
        if (h == 0) __syncthreads();
    }
}

// ---------------------------------------------------------------------------
// NEW: LDS-staged 4-wave 64m x 32n body (l2). Same R8 recipe at small scale:
// per kk the block's 20 distinct frags (4 A + 16 B = all 8 experts x 2u) are
// staged via global_load_lds (5/wave), double-buffered, 1 barrier per kk.
// Cuts per-CU VMEM 64 KB -> 40 KB per kk (2 blocks/CU). LDS 2 x 20 KB
// unions the 36.9 KB f32 epilogue. Output f32 row-major, no act.
// ---------------------------------------------------------------------------
__device__ __forceinline__ void moe_stage_l2(
    char* smem, int bx, int by,
    const unsigned short* __restrict__ Xp,
    const unsigned short* __restrict__ Wp,
    const float* __restrict__ Bias,
    const float* __restrict__ WBl,
    float* __restrict__ Yout,
    int KB, int Dout)
{
    constexpr int UP = 2;
    constexpr int PSTR = 36;                 // epilogue f32 row stride (32+4)
    constexpr unsigned BUFB = 20 * 1024;

    const int tid  = threadIdx.x;
    const int ew   = tid >> 6;               // 0..3 -> experts {2ew, 2ew+1}
    const int l    = tid & 63;
    const int lh   = l >> 4;
    const int ll   = l & 15;
    const int e0   = 2 * ew;
    const int m0   = by * 64;
    const int n0   = bx * 32;
    const int mb   = by >> 1;
    const int half = by & 1;

    f32x4 acc0[4][2], acc1[4][2];
    #pragma unroll
    for (int t = 0; t < 4; ++t)
        #pragma unroll
        for (int u = 0; u < 2; ++u)
            #pragma unroll
            for (int i = 0; i < 4; ++i) { acc0[t][u][i] = 0.f; acc1[t][u][i] = 0.f; }

    // frag table: fid 0..3 = A (half*4+fid); fid 4..19 = B (e=(fid-4)>>1, u=(fid-4)&1)
    const char* xc = (const char*)Xp;
    const char* wc = (const char*)Wp;
    const int fidbase = ew * 5;              // wave wv==ew owns 5 fids
    const char* gp[5]; unsigned kst[5];
    #pragma unroll
    for (int s = 0; s < 5; ++s) {
        const int fid = fidbase + s;
        if (fid < 4) {
            gp[s]  = xc + (unsigned)(mb * KB) * 8192u + (unsigned)(half * 4 + fid) * 1024u + l * 16u;
            kst[s] = 8192u;
        } else {
            const int idx = fid - 4;
            const int e   = idx >> 1;
            const int u   = idx & 1;
            const int fn  = bx * 2 + u;
            const int nb  = fn / UP;
            const int uu  = fn % UP;
            gp[s]  = wc + (unsigned)((nb * KB * 8 + e) * UP + uu) * 1024u + l * 16u;
            kst[s] = UP * 8192u;
        }
    }

    auto STAGE = [&](int b, int kk) {
        char* lb = smem + (unsigned)b * BUFB + (unsigned)fidbase * 1024u;
        #pragma unroll
        for (int s = 0; s < 5; ++s)
            gl_lds(gp[s] + (unsigned)kk * kst[s], lb + s * 1024);
    };

    auto COMPUTE = [&](int b) {
        const char* sb = smem + (unsigned)b * BUFB;
        bf16x8 aR[4], b0R[2], b1R[2];
        #pragma unroll
        for (int t = 0; t < 4; ++t)
            aR[t] = *(const bf16x8*)(sb + t * 1024 + l * 16);
        #pragma unroll
        for (int u = 0; u < 2; ++u) {
            b0R[u] = *(const bf16x8*)(sb + (4 + e0 * 2 + u) * 1024 + l * 16);
            b1R[u] = *(const bf16x8*)(sb + (4 + (e0 + 1) * 2 + u) * 1024 + l * 16);
        }
        __builtin_amdgcn_s_setprio(1);
        #pragma unroll
        for (int u = 0; u < 2; ++u)
            #pragma unroll
            for (int t = 0; t < 4; ++t) {
                acc0[t][u] = __builtin_amdgcn_mfma_f32_16x16x32_bf16(aR[t], b0R[u], acc0[t][u], 0, 0, 0);
                acc1[t][u] = __builtin_amdgcn_mfma_f32_16x16x32_bf16(aR[t], b1R[u], acc1[t][u], 0, 0, 0);
            }
        __builtin_amdgcn_s_setprio(0);
    };

    STAGE(0, 0);
    __syncthreads();
    for (int kk = 0; kk < KB; ++kk) {
        if (kk + 1 < KB) STAGE((kk + 1) & 1, kk + 1);
        COMPUTE(kk & 1);
        __syncthreads();
    }

    // ---- epilogue: hoisted bias/blend, 1 barrier, f32 row-major store ----
    float* epi = (float*)smem;
    float bi0[2], bi1[2];
    #pragma unroll
    for (int u = 0; u < 2; ++u) {
        const int n = n0 + u * 16 + ll;
        bi0[u] = Bias[(size_t)e0 * Dout + n];
        bi1[u] = Bias[(size_t)(e0 + 1) * Dout + n];
    }
    float2 wbp[4][4];
    #pragma unroll
    for (int t = 0; t < 4; ++t)
        #pragma unroll
        for (int r = 0; r < 4; ++r) {
            const int lm = 16 * t + 4 * lh + r;
            wbp[t][r] = ((const float2*)(WBl + (size_t)(m0 + lm) * NEXP))[ew];
        }

    float* pb = epi + ew * (64 * PSTR);
    #pragma unroll
    for (int t = 0; t < 4; ++t)
        #pragma unroll
        for (int r = 0; r < 4; ++r) {
            const int lm = 16 * t + 4 * lh + r;
            #pragma unroll
            for (int u = 0; u < 2; ++u)
                pb[lm * PSTR + u * 16 + ll] =
                    wbp[t][r].x * (acc0[t][u][r] + bi0[u]) + wbp[t][r].y * (acc1[t][u][r] + bi1[u]);
        }
    __syncthreads();

    #pragma unroll
    for (int it = 0; it < 2; ++it) {
        const int idx = tid + 256 * it;          // 512 float4 slots (64x32)
        const int row = idx >> 3;
        const int c4  = (idx & 7) * 4;
        const int rb  = row * PSTR + c4;
        float4 s  = *(const float4*)(epi + 0 * 64 * PSTR + rb);
        float4 q1 = *(const float4*)(epi + 1 * 64 * PSTR + rb);
        float4 q2 = *(const float4*)(epi + 2 * 64 * PSTR + rb);
        float4 q3 = *(const float4*)(epi + 3 * 64 * PSTR + rb);
        s.x += q1.x + q2.x + q3.x;
        s.y += q1.y + q2.y + q3.y;
        s.z += q1.z + q2.z + q3.z;
        s.w += q1.w + q2.w + q3.w;
        *(float4*)(Yout + (size_t)(m0 + row) * Dout + n0 + c4) = s;
    }
}

// ---------------------------------------------------------------------------
// Swizzles (unchanged).
// ---------------------------------------------------------------------------
__device__ __forceinline__ void swz256(int& bx, int& by) {
    const int bid = blockIdx.x;
    const int xcd = bid & 7;
    const int loc = bid >> 3;                // 0..31
    bx = xcd * 2 + (loc & 1);                // 0..15
    by = loc >> 1;                           // 0..15
}
__device__ __forceinline__ void swz_pair(int& bx, int& by) {
    const int bid = blockIdx.x;
    const int xcd = bid & 7;
    const int loc = bid >> 3;                // 0..63
    bx = xcd * 2 + (loc & 1);                // 0..15
    by = loc >> 1;                           // 0..31
}

// Per-layer kernels.
__global__ __launch_bounds__(512, 2) void moe_l0(
    const unsigned short* __restrict__ Xp, const unsigned short* __restrict__ Wp,
    const float* __restrict__ Bias, const float* __restrict__ WBl,
    unsigned short* __restrict__ Yout, int KB, int Dout, int KBn)
{
    __shared__ __align__(16) char smem[2 * 40 * 1024];   // 80 KB
    int bx, by; swz256(bx, by);
    moe_stage<4>(smem, bx, by, Xp, Wp, Bias, WBl, Yout, KB, Dout, KBn);
}
__global__ __launch_bounds__(512, 2) void moe_l1(
    const unsigned short* __restrict__ Xp, const unsigned short* __restrict__ Wp,
    const float* __restrict__ Bias, const float* __restrict__ WBl,
    unsigned short* __restrict__ Yout, int KB, int Dout, int KBn)
{
    __shared__ __align__(16) char smem[2 * 40 * 1024];
    int bx, by; swz256(bx, by);
    moe_stage<4>(smem, bx, by, Xp, Wp, Bias, WBl, Yout, KB, Dout, KBn);
}
// l2: staged 64m x 32n, 512 blocks, 2/CU, f32 out.
__global__ __launch_bounds__(256, 2) void moe_l2(
    const unsigned short* __restrict__ Xp, const unsigned short* __restrict__ Wp,
    const float* __restrict__ Bias, const float* __restrict__ WBl,
    float* __restrict__ Yout, int KB, int Dout)
{
    __shared__ __align__(16) char smem[2 * 20 * 1024];   // 40 KB (>= 36.9 epi)
    int bx, by; swz_pair(bx, by);
    moe_stage_l2(smem, bx, by, Xp, Wp, Bias, WBl, Yout, KB, Dout);
}

// ---------------- fp32 fallback for small ws_size ----------------
#define BM 64
#define BNF 64
#define BKF 16
#define PAD 4

__global__ __launch_bounds__(256) void moe_layer_f32(
    const float* __restrict__ X, const float* __restrict__ W,
    const float* __restrict__ Bias, const float* __restrict__ WB,
    float* __restrict__ Y, int Din, int Dout, int act)
{
    __shared__ float As[BKF][BM + PAD];
    __shared__ float Bs[BKF][BNF + PAD];
    const int tid = threadIdx.x;
    const int tm = tid >> 4, tn = tid & 15;
    const int m0 = blockIdx.y * BM, n0 = blockIdx.x * BNF;
    const int lr = tid >> 2, lc = (tid & 3) << 2;
    float acc[4][4] = {};
    const float* xrow  = X  + (size_t)(m0 + lr) * Din;
    const float* wbrow = WB + (size_t)(m0 + lr) * NEXP;
    const float* wrow0 = W  + (size_t)(n0 + lr) * Din;
    for (int e = 0; e < NEXP; ++e) {
        const float wbe = wbrow[e];
        const float* wrow = wrow0 + (size_t)e * Dout * Din;
        for (int k0 = 0; k0 < Din; k0 += BKF) {
            float4 av = *(const float4*)(xrow + k0 + lc);
            float4 bv = *(const float4*)(wrow + k0 + lc);
            __syncthreads();
            As[lc+0][lr] = av.x*wbe; As[lc+1][lr] = av.y*wbe;
            As[lc+2][lr] = av.z*wbe; As[lc+3][lr] = av.w*wbe;
            Bs[lc+0][lr] = bv.x; Bs[lc+1][lr] = bv.y;
            Bs[lc+2][lr] = bv.z; Bs[lc+3][lr] = bv.w;
            __syncthreads();
            #pragma unroll
            for (int k = 0; k < BKF; ++k) {
                float4 a = *(const float4*)&As[k][tm << 2];
                float4 b = *(const float4*)&Bs[k][tn << 2];
                acc[0][0]+=a.x*b.x; acc[0][1]+=a.x*b.y; acc[0][2]+=a.x*b.z; acc[0][3]+=a.x*b.w;
                acc[1][0]+=a.y*b.x; acc[1][1]+=a.y*b.y; acc[1][2]+=a.y*b.z; acc[1][3]+=a.y*b.w;
                acc[2][0]+=a.z*b.x; acc[2][1]+=a.z*b.y; acc[2][2]+=a.z*b.z; acc[2][3]+=a.z*b.w;
                acc[3][0]+=a.w*b.x; acc[3][1]+=a.w*b.y; acc[3][2]+=a.w*b.z; acc[3][3]+=a.w*b.w;
            }
        }
    }
    #pragma unroll
    for (int im = 0; im < 4; ++im) {
        const int m = m0 + (tm << 2) + im;
        const float* wbm = WB + (size_t)m * NEXP;
        float wv[NEXP];
        #pragma unroll
        for (int e = 0; e < NEXP; ++e) wv[e] = wbm[e];
        #pragma unroll
        for (int in = 0; in < 4; ++in) {
            const int n = n0 + (tn << 2) + in;
            float bsum = 0.f;
            #pragma unroll
            for (int e = 0; e < NEXP; ++e) bsum += wv[e] * Bias[(size_t)e * Dout + n];
            float v = acc[im][in] + bsum;
            if (act) v = v > 0.f ? v : expm1f(v);
            acc[im][in] = v;
        }
        float4 o = make_float4(acc[im][0], acc[im][1], acc[im][2], acc[im][3]);
        *(float4*)(Y + (size_t)m * Dout + n0 + (tn << 2)) = o;
    }
}

extern "C" void kernel_launch(void* const* d_in, const int* in_sizes, int n_in,
                              void* d_out, int out_size, void* d_ws, size_t ws_size,
                              hipStream_t stream)
{
    (void)in_sizes; (void)n_in; (void)out_size;
    const float* wb = (const float*)d_in[0];
    const float* x  = (const float*)d_in[1];
    const float* W0 = (const float*)d_in[2];
    const float* B0 = (const float*)d_in[3];
    const float* W1 = (const float*)d_in[4];
    const float* B1 = (const float*)d_in[5];
    const float* W2 = (const float*)d_in[6];
    const float* B2 = (const float*)d_in[7];
    float* out = (float*)d_out;

    const size_t NW0 = (size_t)8*1024*512, NW1 = (size_t)8*1024*1024, NW2 = (size_t)8*512*1024;
    const size_t NX0 = (size_t)BATCH*512, NX1 = (size_t)BATCH*1024;
    const size_t need = (NW0 + NW1 + NW2 + NX0 + 2 * NX1) * 2;   // ~44 MB bf16

    if (ws_size >= need) {
        unsigned short* W0p = (unsigned short*)d_ws;
        unsigned short* W1p = W0p + NW0;
        unsigned short* W2p = W1p + NW1;
        unsigned short* x0p = W2p + NW2;
        unsigned short* x1p = x0p + NX0;
        unsigned short* x2p = x1p + NX1;
        pack_all<<<10496, 256, 0, stream>>>(W0, W1, W2, x, W0p, W1p, W2p, x0p);
        moe_l0<<<256, 512, 0, stream>>>(x0p, W0p, B0, wb, x1p, 16, 1024, 32);
        moe_l1<<<256, 512, 0, stream>>>(x1p, W1p, B1, wb, x2p, 32, 1024, 32);
        moe_l2<<<512, 256, 0, stream>>>(x2p, W2p, B2, wb, out, 32, 512);
    } else {
        float* x1 = (float*)d_ws;
        float* x2 = x1 + (size_t)BATCH * 1024;
        moe_layer_f32<<<dim3(1024/BNF, BATCH/BM), 256, 0, stream>>>(x,  W0, B0, wb, x1, 512,  1024, 1);
        moe_layer_f32<<<dim3(1024/BNF, BATCH/BM), 256, 0, stream>>>(x1, W1, B1, wb, x2, 1024, 1024, 1);
        moe_layer_f32<<<dim3(512/BNF,  BATCH/BM), 256, 0, stream>>>(x2, W2, B2, wb, out, 1024, 512,  0);
    }
}